// Round 3
// baseline (77.753 us; speedup 1.0000x reference)
//
#include <hip/hip_runtime.h>
#include <hip/hip_bf16.h>

#define N_NODES 2048
#define EMBED 256
#define STATE 128
#define HID 256
#define N_ACT 256
#define TEAMS 8
#define PAIR_F 14
#define BT_TOTAL 512               // B*T
#define M_TOTAL (BT_TOTAL * N_ACT) // 131072

typedef _Float16 f16_t;
typedef _Float16 f16x8 __attribute__((ext_vector_type(8)));
typedef _Float16 f16x4 __attribute__((ext_vector_type(4)));
typedef float f32x4 __attribute__((ext_vector_type(4)));

// reordered weight layout: for (k, n), KB = K/32:
//   g=n>>4, kb=k>>5, q=(k>>3)&3, c=n&15, j=k&7
//   flat = ((g*KB + kb)*4 + q)*128 + c*8 + j
// -> a wave (lanes c,q) reading frag (g, kb) touches contiguous 2KB. Coalesced.
__device__ __forceinline__ size_t reord_idx(int k, int n, int KB) {
    return (size_t)(((n >> 4) * KB + (k >> 5)) * 4 + ((k >> 3) & 3)) * 128 +
           (size_t)(n & 15) * 8 + (k & 7);
}

// ---------------- precompute: column partial sums ----------------
__global__ void k_colsum_part(const float* __restrict__ ne, float* __restrict__ gpart) {
    int b = blockIdx.x;
    int t = threadIdx.x;
    float s = 0.f;
    const float* base = ne + (size_t)b * 32 * EMBED + t;
#pragma unroll
    for (int i = 0; i < 32; ++i) s += base[(size_t)i * EMBED];
    gpart[b * EMBED + t] = s;
}

// ---------------- precompute: gathers + weight reorders (one launch) ----------------
// seg0 vecs_h  [256][768] f16 : [proc | team | gmean]
// seg1 W1abcT  reorder W1[0:768]    KB=24
// seg2 W1dT    reorder W1[768:1024] KB=8
// seg3 WsT     reorder Ws           KB=4
// seg4 W2s     reorder W2           KB=8
// seg5 w1pt    reorder W1[1024:1038] pad K->32, KB=1
// seg6 states_h f16 copy
__global__ void k_prep(const float* __restrict__ ne, const int* __restrict__ idx,
                       const float* __restrict__ team, const float* __restrict__ gpart,
                       const float* __restrict__ states, const float* __restrict__ Ws,
                       const float* __restrict__ W1, const float* __restrict__ W2,
                       f16_t* __restrict__ vecs, f16_t* __restrict__ W1abcT,
                       f16_t* __restrict__ W1dT, f16_t* __restrict__ WsT,
                       f16_t* __restrict__ W2s, f16_t* __restrict__ w1pt,
                       f16_t* __restrict__ states_h) {
    int i = blockIdx.x * 256 + threadIdx.x;
    if (i < 196608) { // vecs
        int a = i / 768, e = i - a * 768;
        float v;
        if (e < 256) v = ne[(size_t)idx[a] * EMBED + e];
        else if (e < 512) v = team[(a % TEAMS) * EMBED + (e - 256)];
        else {
            int h = e - 512;
            float s = 0.f;
#pragma unroll 8
            for (int p = 0; p < 64; ++p) s += gpart[p * EMBED + h];
            v = s * (1.0f / N_NODES);
        }
        vecs[(size_t)a * 768 + e] = (f16_t)v;
        return;
    }
    i -= 196608;
    if (i < 196608) { // W1abcT
        int k = i >> 8, n = i & 255;
        W1abcT[reord_idx(k, n, 24)] = (f16_t)W1[(size_t)k * HID + n];
        return;
    }
    i -= 196608;
    if (i < 65536) { // W1dT
        int k = i >> 8, n = i & 255;
        W1dT[reord_idx(k, n, 8)] = (f16_t)W1[(size_t)(768 + k) * HID + n];
        return;
    }
    i -= 65536;
    if (i < 32768) { // WsT
        int k = i >> 8, n = i & 255;
        WsT[reord_idx(k, n, 4)] = (f16_t)Ws[(size_t)k * EMBED + n];
        return;
    }
    i -= 32768;
    if (i < 65536) { // W2s
        int k = i >> 8, n = i & 255;
        W2s[reord_idx(k, n, 8)] = (f16_t)W2[(size_t)k * HID + n];
        return;
    }
    i -= 65536;
    if (i < 8192) { // w1pt (pad to K=32)
        int k = i >> 8, n = i & 255;
        float v = (k < PAIR_F) ? W1[(size_t)(1024 + k) * HID + n] : 0.f;
        w1pt[reord_idx(k, n, 1)] = (f16_t)v;
        return;
    }
    i -= 8192;
    if (i < 65536) states_h[i] = (f16_t)states[i];
}

// ---------------- generic 64x64-tile fp16 GEMM (4 waves, wave = 64x16) ----------------
__device__ __forceinline__ void gemm_tile64(const f16_t* __restrict__ A, int K, int KB,
                                            const f16_t* __restrict__ Bre,
                                            const float* __restrict__ bias, bool relu,
                                            f16_t* __restrict__ out, int m0, int n0) {
    const int tid = threadIdx.x;
    const int wid = tid >> 6, lane = tid & 63;
    const int c = lane & 15, q = lane >> 4;
    const int n = n0 + wid * 16 + c;
    const int g = n >> 4;
    f32x4 acc[4] = {f32x4{0,0,0,0}, f32x4{0,0,0,0}, f32x4{0,0,0,0}, f32x4{0,0,0,0}};
    for (int ks = 0; ks < KB; ++ks) {
        f16x8 bf = *(const f16x8*)(Bre + (size_t)((g * KB + ks) * 4 + q) * 128 + c * 8);
#pragma unroll
        for (int mi = 0; mi < 4; ++mi) {
            f16x8 af = *(const f16x8*)(A + (size_t)(m0 + mi * 16 + c) * K + ks * 32 + q * 8);
            acc[mi] = __builtin_amdgcn_mfma_f32_16x16x32_f16(af, bf, acc[mi], 0, 0, 0);
        }
    }
    float bv = bias ? bias[n] : 0.f;
#pragma unroll
    for (int mi = 0; mi < 4; ++mi)
#pragma unroll
        for (int j = 0; j < 4; ++j) {
            float v = acc[mi][j] + bv;
            if (relu) v = fmaxf(v, 0.f);
            out[(size_t)(m0 + mi * 16 + q * 4 + j) * HID + n] = (f16_t)v;
        }
}

// se = relu(states@Ws + bs)  [512x256]   blocks 0..31
// pa = vecs@W1abc + b1       [256x256]   blocks 32..47
__global__ __launch_bounds__(256, 4) void k_sepa(
    const f16_t* __restrict__ states_h, const f16_t* __restrict__ WsT,
    const float* __restrict__ bs, const f16_t* __restrict__ vecs,
    const f16_t* __restrict__ W1abcT, const float* __restrict__ b1,
    f16_t* __restrict__ se, f16_t* __restrict__ pa_h) {
    int bid = blockIdx.x;
    if (bid < 32) gemm_tile64(states_h, 128, 4, WsT, bs, true, se, (bid >> 2) * 64, (bid & 3) * 64);
    else {
        int b = bid - 32;
        gemm_tile64(vecs, 768, 24, W1abcT, b1, false, pa_h, (b >> 2) * 64, (b & 3) * 64);
    }
}

// pbt = se@W1d  [512x256]
__global__ __launch_bounds__(256, 4) void k_pbtk(const f16_t* __restrict__ se,
                                                 const f16_t* __restrict__ W1dT,
                                                 f16_t* __restrict__ pbt_h) {
    int b = blockIdx.x;
    gemm_tile64(se, 256, 8, W1dT, nullptr, false, pbt_h, (b >> 2) * 64, (b & 3) * 64);
}

// ---------------- fused main kernel ----------------
// block: 256 thr / 4 waves; tile 128 rows x 256 cols; wave tile = 128x64.
// phase 1 (transposed pair GEMM + pa + pbt + relu -> fp16 LDS, XOR-swizzled)
// phase 2 (h1 @ W2, fp16 single pass), fused relu+b2+W3 epilogue.
__global__ __launch_bounds__(256, 2) void k_main(
    const float* __restrict__ pf, const f16_t* __restrict__ pa,
    const f16_t* __restrict__ pbt, const f16_t* __restrict__ w2s,
    const f16_t* __restrict__ w1pt, const float* __restrict__ b2,
    const float* __restrict__ W3, const float* __restrict__ b3,
    float* __restrict__ out) {
    __shared__ __align__(16) f16_t Ah[128 * 256];
    __shared__ float red[4][128];

    const int tid = threadIdx.x;
    const int wid = tid >> 6, lane = tid & 63;
    const int c = lane & 15, q = lane >> 4;

    const int r0 = blockIdx.x * 128;
    const int bt = r0 >> 8;
    const int a0 = r0 & 255;

    // epilogue constants (phase-2 layout: n = wid*64 + ni*16 + c)
    float b2v[4], w3v[4];
#pragma unroll
    for (int ni = 0; ni < 4; ++ni) {
        int n = wid * 64 + ni * 16 + c;
        b2v[ni] = b2[n];
        w3v[ni] = W3[n];
    }
    // pbt (phase-1 layout: n = wid*64 + nf*16 + q*4 + j)
    float pbtv[4][4];
#pragma unroll
    for (int nf = 0; nf < 4; ++nf) {
        f16x4 t = *(const f16x4*)(pbt + (size_t)bt * HID + wid * 64 + nf * 16 + q * 4);
#pragma unroll
        for (int j = 0; j < 4; ++j) pbtv[nf][j] = (float)t[j];
    }

    f32x4 acc[32];
#pragma unroll
    for (int i = 0; i < 32; ++i) acc[i] = f32x4{0, 0, 0, 0};

    // ---- phase 1: transposed pair GEMM: D[n][m] = w1pt (A) x pf^T (B)
    f16x8 af[4];
#pragma unroll
    for (int nf = 0; nf < 4; ++nf) {
        int g = wid * 4 + nf;
        af[nf] = *(const f16x8*)(w1pt + (size_t)(g * 4 + q) * 128 + c * 8);
    }
#pragma unroll
    for (int mf = 0; mf < 8; ++mf) {
        int m = mf * 16 + c;
        const float* row = pf + (size_t)(r0 + m) * PAIR_F;
        float2 v01{0, 0}, v23{0, 0}, v45{0, 0}, v67{0, 0};
        if (q == 0) {
            v01 = *(const float2*)(row);
            v23 = *(const float2*)(row + 2);
            v45 = *(const float2*)(row + 4);
            v67 = *(const float2*)(row + 6);
        } else if (q == 1) {
            v01 = *(const float2*)(row + 8);
            v23 = *(const float2*)(row + 10);
            v45 = *(const float2*)(row + 12); // k=12,13; rest padded 0
        }
        f16x8 bf;
        bf[0] = (f16_t)v01.x; bf[1] = (f16_t)v01.y;
        bf[2] = (f16_t)v23.x; bf[3] = (f16_t)v23.y;
        bf[4] = (f16_t)v45.x; bf[5] = (f16_t)v45.y;
        bf[6] = (f16_t)v67.x; bf[7] = (f16_t)v67.y;
#pragma unroll
        for (int nf = 0; nf < 4; ++nf)
            acc[nf * 8 + mf] = __builtin_amdgcn_mfma_f32_16x16x32_f16(af[nf], bf, acc[nf * 8 + mf], 0, 0, 0);
    }

    // ---- h1 = relu(pair + pa + pbt) -> fp16, swizzled LDS (row m, k' = n ^ ((m&7)<<3))
#pragma unroll
    for (int nf = 0; nf < 4; ++nf) {
        int n0 = wid * 64 + nf * 16 + q * 4;
#pragma unroll
        for (int mf = 0; mf < 8; ++mf) {
            int m = mf * 16 + c;
            f16x4 pav = *(const f16x4*)(pa + (size_t)(a0 + m) * HID + n0);
            f16x4 hv;
#pragma unroll
            for (int j = 0; j < 4; ++j) {
                float h = acc[nf * 8 + mf][j] + (float)pav[j] + pbtv[nf][j];
                hv[j] = (f16_t)fmaxf(h, 0.f);
            }
            *(f16x4*)(&Ah[m * 256 + (n0 ^ ((m & 7) << 3))]) = hv;
        }
    }

#pragma unroll
    for (int i = 0; i < 32; ++i) acc[i] = f32x4{0, 0, 0, 0};

    __syncthreads();

    // ---- phase 2: h2 = h1[128x256] @ W2[256x256], fp16 single pass
#pragma unroll
    for (int ks = 0; ks < 8; ++ks) {
        f16x8 bh[4];
#pragma unroll
        for (int ni = 0; ni < 4; ++ni) {
            int g = wid * 4 + ni;
            bh[ni] = *(const f16x8*)(w2s + (size_t)((g * 8 + ks) * 4 + q) * 128 + c * 8);
        }
#pragma unroll
        for (int mi = 0; mi < 8; ++mi) {
            int m = mi * 16 + c;
            int kx = (ks * 32 + q * 8) ^ ((m & 7) << 3);
            f16x8 ah = *(const f16x8*)(&Ah[m * 256 + kx]);
#pragma unroll
            for (int ni = 0; ni < 4; ++ni)
                acc[mi * 4 + ni] = __builtin_amdgcn_mfma_f32_16x16x32_f16(ah, bh[ni], acc[mi * 4 + ni], 0, 0, 0);
        }
    }

    // ---- epilogue: score[m] = sum_n relu(h2 + b2) * W3  (+ b3)
    float p[8][4];
#pragma unroll
    for (int mi = 0; mi < 8; ++mi)
#pragma unroll
        for (int j = 0; j < 4; ++j) {
            float s = 0.f;
#pragma unroll
            for (int ni = 0; ni < 4; ++ni)
                s = fmaf(fmaxf(acc[mi * 4 + ni][j] + b2v[ni], 0.f), w3v[ni], s);
            p[mi][j] = s;
        }
#pragma unroll
    for (int off = 1; off < 16; off <<= 1)
#pragma unroll
        for (int mi = 0; mi < 8; ++mi)
#pragma unroll
            for (int j = 0; j < 4; ++j) p[mi][j] += __shfl_xor(p[mi][j], off, 64);

    if (c == 0) {
#pragma unroll
        for (int mi = 0; mi < 8; ++mi)
#pragma unroll
            for (int j = 0; j < 4; ++j) red[wid][mi * 16 + q * 4 + j] = p[mi][j];
    }
    __syncthreads();

    if (tid < 128) {
        out[(size_t)r0 + tid] = red[0][tid] + red[1][tid] + red[2][tid] + red[3][tid] + b3[0];
    }
}

// ---------------- launch ----------------
extern "C" void kernel_launch(void* const* d_in, const int* in_sizes, int n_in,
                              void* d_out, int out_size, void* d_ws, size_t ws_size,
                              hipStream_t stream) {
    (void)in_sizes; (void)n_in; (void)out_size; (void)ws_size;
    const float* ne     = (const float*)d_in[0];
    const float* states = (const float*)d_in[1];
    const float* pf     = (const float*)d_in[2];
    const int*   idx    = (const int*)d_in[3];
    const float* team   = (const float*)d_in[4];
    const float* Ws     = (const float*)d_in[5];
    const float* bs     = (const float*)d_in[6];
    const float* W1     = (const float*)d_in[7];
    const float* b1     = (const float*)d_in[8];
    const float* W2     = (const float*)d_in[9];
    const float* b2     = (const float*)d_in[10];
    const float* W3     = (const float*)d_in[11];
    const float* b3     = (const float*)d_in[12];
    float* out = (float*)d_out;

    char* ws = (char*)d_ws;
    float* gpart    = (float*)(ws + 0);        // 65536
    f16_t* vecs     = (f16_t*)(ws + 65536);    // 393216
    f16_t* W1abcT   = (f16_t*)(ws + 458752);   // 393216
    f16_t* W1dT     = (f16_t*)(ws + 851968);   // 131072
    f16_t* WsT      = (f16_t*)(ws + 983040);   // 65536
    f16_t* W2s      = (f16_t*)(ws + 1048576);  // 131072
    f16_t* w1pt     = (f16_t*)(ws + 1179648);  // 16384
    f16_t* states_h = (f16_t*)(ws + 1196032);  // 131072
    f16_t* se       = (f16_t*)(ws + 1327104);  // 262144
    f16_t* pa_h     = (f16_t*)(ws + 1589248);  // 131072
    f16_t* pbt_h    = (f16_t*)(ws + 1720320);  // 262144  (end 1982464)

    k_colsum_part<<<64, 256, 0, stream>>>(ne, gpart);
    k_prep<<<2464, 256, 0, stream>>>(ne, idx, team, gpart, states, Ws, W1, W2,
                                     vecs, W1abcT, W1dT, WsT, W2s, w1pt, states_h);
    k_sepa<<<48, 256, 0, stream>>>(states_h, WsT, bs, vecs, W1abcT, b1, se, pa_h);
    k_pbtk<<<32, 256, 0, stream>>>(se, W1dT, pbt_h);
    k_main<<<M_TOTAL / 128, 256, 0, stream>>>(pf, pa_h, pbt_h, W2s, w1pt, b2, W3, b3, out);
}

// Round 4
// 68.998 us; speedup vs baseline: 1.1269x; 1.1269x over previous
//
#include <hip/hip_runtime.h>
#include <hip/hip_bf16.h>

#define N_NODES 2048
#define EMBED 256
#define STATE 128
#define HID 256
#define N_ACT 256
#define TEAMS 8
#define PAIR_F 14
#define BT_TOTAL 512               // B*T
#define M_TOTAL (BT_TOTAL * N_ACT) // 131072

typedef _Float16 f16_t;
typedef _Float16 f16x8 __attribute__((ext_vector_type(8)));
typedef _Float16 f16x4 __attribute__((ext_vector_type(4)));
typedef float f32x4 __attribute__((ext_vector_type(4)));

// reordered weight layout: for (k, n), KB = K/32:
//   g=n>>4, kb=k>>5, q=(k>>3)&3, c=n&15, j=k&7
//   flat = ((g*KB + kb)*4 + q)*128 + c*8 + j
__device__ __forceinline__ size_t reord_idx(int k, int n, int KB) {
    return (size_t)(((n >> 4) * KB + (k >> 5)) * 4 + ((k >> 3) & 3)) * 128 +
           (size_t)(n & 15) * 8 + (k & 7);
}

// ---------------- precompute: column partial sums ----------------
__global__ void k_colsum_part(const float* __restrict__ ne, float* __restrict__ gpart) {
    int b = blockIdx.x;
    int t = threadIdx.x;
    float s = 0.f;
    const float* base = ne + (size_t)b * 32 * EMBED + t;
#pragma unroll
    for (int i = 0; i < 32; ++i) s += base[(size_t)i * EMBED];
    gpart[b * EMBED + t] = s;
}

// ---------------- precompute: gathers + weight reorders (one launch) ----------------
__global__ void k_prep(const float* __restrict__ ne, const int* __restrict__ idx,
                       const float* __restrict__ team, const float* __restrict__ gpart,
                       const float* __restrict__ states, const float* __restrict__ Ws,
                       const float* __restrict__ W1, const float* __restrict__ W2,
                       f16_t* __restrict__ vecs, f16_t* __restrict__ W1abcT,
                       f16_t* __restrict__ W1dT, f16_t* __restrict__ WsT,
                       f16_t* __restrict__ W2s, f16_t* __restrict__ w1pt,
                       f16_t* __restrict__ states_h) {
    int i = blockIdx.x * 256 + threadIdx.x;
    if (i < 196608) { // vecs
        int a = i / 768, e = i - a * 768;
        float v;
        if (e < 256) v = ne[(size_t)idx[a] * EMBED + e];
        else if (e < 512) v = team[(a % TEAMS) * EMBED + (e - 256)];
        else {
            int h = e - 512;
            float s = 0.f;
#pragma unroll 8
            for (int p = 0; p < 64; ++p) s += gpart[p * EMBED + h];
            v = s * (1.0f / N_NODES);
        }
        vecs[(size_t)a * 768 + e] = (f16_t)v;
        return;
    }
    i -= 196608;
    if (i < 196608) { // W1abcT
        int k = i >> 8, n = i & 255;
        W1abcT[reord_idx(k, n, 24)] = (f16_t)W1[(size_t)k * HID + n];
        return;
    }
    i -= 196608;
    if (i < 65536) { // W1dT
        int k = i >> 8, n = i & 255;
        W1dT[reord_idx(k, n, 8)] = (f16_t)W1[(size_t)(768 + k) * HID + n];
        return;
    }
    i -= 65536;
    if (i < 32768) { // WsT
        int k = i >> 8, n = i & 255;
        WsT[reord_idx(k, n, 4)] = (f16_t)Ws[(size_t)k * EMBED + n];
        return;
    }
    i -= 32768;
    if (i < 65536) { // W2s
        int k = i >> 8, n = i & 255;
        W2s[reord_idx(k, n, 8)] = (f16_t)W2[(size_t)k * HID + n];
        return;
    }
    i -= 65536;
    if (i < 8192) { // w1pt (pad to K=32)
        int k = i >> 8, n = i & 255;
        float v = (k < PAIR_F) ? W1[(size_t)(1024 + k) * HID + n] : 0.f;
        w1pt[reord_idx(k, n, 1)] = (f16_t)v;
        return;
    }
    i -= 8192;
    if (i < 65536) states_h[i] = (f16_t)states[i];
}

// ---------------- generic 64x64-tile fp16 GEMM (4 waves, wave = 64x16) ----------------
__device__ __forceinline__ void gemm_tile64(const f16_t* __restrict__ A, int K, int KB,
                                            const f16_t* __restrict__ Bre,
                                            const float* __restrict__ bias, bool relu,
                                            f16_t* __restrict__ out, int m0, int n0) {
    const int tid = threadIdx.x;
    const int wid = tid >> 6, lane = tid & 63;
    const int c = lane & 15, q = lane >> 4;
    const int n = n0 + wid * 16 + c;
    const int g = n >> 4;
    f32x4 acc[4] = {f32x4{0,0,0,0}, f32x4{0,0,0,0}, f32x4{0,0,0,0}, f32x4{0,0,0,0}};
    for (int ks = 0; ks < KB; ++ks) {
        f16x8 bf = *(const f16x8*)(Bre + (size_t)((g * KB + ks) * 4 + q) * 128 + c * 8);
#pragma unroll
        for (int mi = 0; mi < 4; ++mi) {
            f16x8 af = *(const f16x8*)(A + (size_t)(m0 + mi * 16 + c) * K + ks * 32 + q * 8);
            acc[mi] = __builtin_amdgcn_mfma_f32_16x16x32_f16(af, bf, acc[mi], 0, 0, 0);
        }
    }
    float bv = bias ? bias[n] : 0.f;
#pragma unroll
    for (int mi = 0; mi < 4; ++mi)
#pragma unroll
        for (int j = 0; j < 4; ++j) {
            float v = acc[mi][j] + bv;
            if (relu) v = fmaxf(v, 0.f);
            out[(size_t)(m0 + mi * 16 + q * 4 + j) * HID + n] = (f16_t)v;
        }
}

// ---------------- fused pa + pbt kernel ----------------
// blocks 0..7 : pbt tile (64 rows of bt): se = relu(states@Ws+bs) in LDS, pbt = se@W1d
// blocks 8..23: pa = vecs@W1abc + b1 (64x64 tiles)
__global__ __launch_bounds__(256, 4) void k_pp(
    const f16_t* __restrict__ states_h, const f16_t* __restrict__ WsT,
    const float* __restrict__ bs, const f16_t* __restrict__ W1dT,
    const f16_t* __restrict__ vecs, const f16_t* __restrict__ W1abcT,
    const float* __restrict__ b1, f16_t* __restrict__ pa_h,
    f16_t* __restrict__ pbt_h) {
    __shared__ __align__(16) f16_t se[64 * 256];
    int bid = blockIdx.x;
    if (bid >= 8) {
        int b = bid - 8;
        gemm_tile64(vecs, 768, 24, W1abcT, b1, false, pa_h, (b >> 2) * 64, (b & 3) * 64);
        return;
    }
    const int tid = threadIdx.x;
    const int wid = tid >> 6, lane = tid & 63;
    const int c = lane & 15, q = lane >> 4;
    const int bt0 = bid * 64;

    f32x4 acc[4][4];
#pragma unroll
    for (int mi = 0; mi < 4; ++mi)
#pragma unroll
        for (int ni = 0; ni < 4; ++ni) acc[mi][ni] = f32x4{0, 0, 0, 0};

    // phase A: se = relu(states@Ws + bs), 64x256, wave covers 64-col quarter
#pragma unroll
    for (int ks = 0; ks < 4; ++ks) {
        f16x8 bh[4];
#pragma unroll
        for (int ni = 0; ni < 4; ++ni) {
            int g = wid * 4 + ni;
            bh[ni] = *(const f16x8*)(WsT + (size_t)((g * 4 + ks) * 4 + q) * 128 + c * 8);
        }
#pragma unroll
        for (int mi = 0; mi < 4; ++mi) {
            f16x8 af = *(const f16x8*)(states_h + (size_t)(bt0 + mi * 16 + c) * STATE + ks * 32 + q * 8);
#pragma unroll
            for (int ni = 0; ni < 4; ++ni)
                acc[mi][ni] = __builtin_amdgcn_mfma_f32_16x16x32_f16(af, bh[ni], acc[mi][ni], 0, 0, 0);
        }
    }
    float bsv[4];
#pragma unroll
    for (int ni = 0; ni < 4; ++ni) bsv[ni] = bs[wid * 64 + ni * 16 + c];
#pragma unroll
    for (int mi = 0; mi < 4; ++mi)
#pragma unroll
        for (int ni = 0; ni < 4; ++ni)
#pragma unroll
            for (int j = 0; j < 4; ++j) {
                int m = mi * 16 + q * 4 + j;
                int n = wid * 64 + ni * 16 + c;
                se[m * 256 + (n ^ ((m & 7) << 3))] = (f16_t)fmaxf(acc[mi][ni][j] + bsv[ni], 0.f);
            }
#pragma unroll
    for (int mi = 0; mi < 4; ++mi)
#pragma unroll
        for (int ni = 0; ni < 4; ++ni) acc[mi][ni] = f32x4{0, 0, 0, 0};
    __syncthreads();

    // phase B: pbt = se @ W1d  (K=256)
#pragma unroll
    for (int ks = 0; ks < 8; ++ks) {
        f16x8 bh[4];
#pragma unroll
        for (int ni = 0; ni < 4; ++ni) {
            int g = wid * 4 + ni;
            bh[ni] = *(const f16x8*)(W1dT + (size_t)((g * 8 + ks) * 4 + q) * 128 + c * 8);
        }
#pragma unroll
        for (int mi = 0; mi < 4; ++mi) {
            int m = mi * 16 + c;
            f16x8 ah = *(const f16x8*)(&se[m * 256 + ((ks * 32 + q * 8) ^ ((m & 7) << 3))]);
#pragma unroll
            for (int ni = 0; ni < 4; ++ni)
                acc[mi][ni] = __builtin_amdgcn_mfma_f32_16x16x32_f16(ah, bh[ni], acc[mi][ni], 0, 0, 0);
        }
    }
#pragma unroll
    for (int mi = 0; mi < 4; ++mi)
#pragma unroll
        for (int ni = 0; ni < 4; ++ni)
#pragma unroll
            for (int j = 0; j < 4; ++j)
                pbt_h[(size_t)(bt0 + mi * 16 + q * 4 + j) * HID + wid * 64 + ni * 16 + c] =
                    (f16_t)acc[mi][ni][j];
}

// ---------------- fused main kernel ----------------
// 512 threads / 8 waves; tile 128 rows x 256 cols; wave tile 64x64.
// wave (wr,wc): wr = wid>>2 row-half, wc = wid&3 col-quarter.
__global__ __launch_bounds__(512, 4) void k_main(
    const float* __restrict__ pf, const f16_t* __restrict__ pa,
    const f16_t* __restrict__ pbt, const f16_t* __restrict__ w2s,
    const f16_t* __restrict__ w1pt, const float* __restrict__ b2,
    const float* __restrict__ W3, const float* __restrict__ b3,
    float* __restrict__ out) {
    __shared__ __align__(16) f16_t Ah[128 * 256];
    __shared__ float red[4][128];

    const int tid = threadIdx.x;
    const int wid = tid >> 6, lane = tid & 63;
    const int wr = wid >> 2, wc = wid & 3;
    const int c = lane & 15, q = lane >> 4;

    const int r0 = blockIdx.x * 128;
    const int bt = r0 >> 8;
    const int a0 = r0 & 255;

    // epilogue constants (phase-2 layout: n = wc*64 + ni*16 + c)
    float b2v[4], w3v[4];
#pragma unroll
    for (int ni = 0; ni < 4; ++ni) {
        int n = wc * 64 + ni * 16 + c;
        b2v[ni] = b2[n];
        w3v[ni] = W3[n];
    }
    // pbt (phase-1 layout: n = wc*64 + nf*16 + q*4 + j)
    f16x4 pbtv[4];
#pragma unroll
    for (int nf = 0; nf < 4; ++nf)
        pbtv[nf] = *(const f16x4*)(pbt + (size_t)bt * HID + wc * 64 + nf * 16 + q * 4);

    f32x4 acc[16];
#pragma unroll
    for (int i = 0; i < 16; ++i) acc[i] = f32x4{0, 0, 0, 0};

    // ---- phase 1: transposed pair GEMM: D[n][m] = w1pt (A) x pf^T (B)
    f16x8 af[4];
#pragma unroll
    for (int nf = 0; nf < 4; ++nf) {
        int g = wc * 4 + nf;
        af[nf] = *(const f16x8*)(w1pt + (size_t)(g * 4 + q) * 128 + c * 8);
    }
#pragma unroll
    for (int mf = 0; mf < 4; ++mf) {
        int m = wr * 64 + mf * 16 + c;
        const float* row = pf + (size_t)(r0 + m) * PAIR_F;
        float2 v01{0, 0}, v23{0, 0}, v45{0, 0}, v67{0, 0};
        if (q == 0) {
            v01 = *(const float2*)(row);
            v23 = *(const float2*)(row + 2);
            v45 = *(const float2*)(row + 4);
            v67 = *(const float2*)(row + 6);
        } else if (q == 1) {
            v01 = *(const float2*)(row + 8);
            v23 = *(const float2*)(row + 10);
            v45 = *(const float2*)(row + 12); // k=12,13; rest padded 0
        }
        f16x8 bf;
        bf[0] = (f16_t)v01.x; bf[1] = (f16_t)v01.y;
        bf[2] = (f16_t)v23.x; bf[3] = (f16_t)v23.y;
        bf[4] = (f16_t)v45.x; bf[5] = (f16_t)v45.y;
        bf[6] = (f16_t)v67.x; bf[7] = (f16_t)v67.y;
#pragma unroll
        for (int nf = 0; nf < 4; ++nf)
            acc[nf * 4 + mf] = __builtin_amdgcn_mfma_f32_16x16x32_f16(af[nf], bf, acc[nf * 4 + mf], 0, 0, 0);
    }

    // ---- h1 = relu(pair + pa + pbt) -> fp16, swizzled LDS
#pragma unroll
    for (int nf = 0; nf < 4; ++nf) {
        int n0 = wc * 64 + nf * 16 + q * 4;
#pragma unroll
        for (int mf = 0; mf < 4; ++mf) {
            int m = wr * 64 + mf * 16 + c;
            f16x4 pav = *(const f16x4*)(pa + (size_t)(a0 + m) * HID + n0);
            f16x4 hv;
#pragma unroll
            for (int j = 0; j < 4; ++j) {
                float h = acc[nf * 4 + mf][j] + (float)pav[j] + (float)pbtv[nf][j];
                hv[j] = (f16_t)fmaxf(h, 0.f);
            }
            *(f16x4*)(&Ah[m * 256 + (n0 ^ ((m & 7) << 3))]) = hv;
        }
    }

#pragma unroll
    for (int i = 0; i < 16; ++i) acc[i] = f32x4{0, 0, 0, 0};

    __syncthreads();

    // ---- phase 2: h2 = h1[128x256] @ W2[256x256]; wave computes 64x64
#pragma unroll
    for (int ks = 0; ks < 8; ++ks) {
        f16x8 bh[4];
#pragma unroll
        for (int ni = 0; ni < 4; ++ni) {
            int g = wc * 4 + ni;
            bh[ni] = *(const f16x8*)(w2s + (size_t)((g * 8 + ks) * 4 + q) * 128 + c * 8);
        }
#pragma unroll
        for (int mi = 0; mi < 4; ++mi) {
            int m = wr * 64 + mi * 16 + c;
            int kx = (ks * 32 + q * 8) ^ ((m & 7) << 3);
            f16x8 ah = *(const f16x8*)(&Ah[m * 256 + kx]);
#pragma unroll
            for (int ni = 0; ni < 4; ++ni)
                acc[mi * 4 + ni] = __builtin_amdgcn_mfma_f32_16x16x32_f16(ah, bh[ni], acc[mi * 4 + ni], 0, 0, 0);
        }
    }

    // ---- epilogue: score[m] = sum_n relu(h2 + b2) * W3  (+ b3)
    float p[4][4];
#pragma unroll
    for (int mi = 0; mi < 4; ++mi)
#pragma unroll
        for (int j = 0; j < 4; ++j) {
            float s = 0.f;
#pragma unroll
            for (int ni = 0; ni < 4; ++ni)
                s = fmaf(fmaxf(acc[mi * 4 + ni][j] + b2v[ni], 0.f), w3v[ni], s);
            p[mi][j] = s;
        }
#pragma unroll
    for (int off = 1; off < 16; off <<= 1)
#pragma unroll
        for (int mi = 0; mi < 4; ++mi)
#pragma unroll
            for (int j = 0; j < 4; ++j) p[mi][j] += __shfl_xor(p[mi][j], off, 64);

    if (c == 0) {
#pragma unroll
        for (int mi = 0; mi < 4; ++mi)
#pragma unroll
            for (int j = 0; j < 4; ++j)
                red[wc][wr * 64 + mi * 16 + q * 4 + j] = p[mi][j];
    }
    __syncthreads();

    if (tid < 128) {
        out[(size_t)r0 + tid] = red[0][tid] + red[1][tid] + red[2][tid] + red[3][tid] + b3[0];
    }
}

// ---------------- launch ----------------
extern "C" void kernel_launch(void* const* d_in, const int* in_sizes, int n_in,
                              void* d_out, int out_size, void* d_ws, size_t ws_size,
                              hipStream_t stream) {
    (void)in_sizes; (void)n_in; (void)out_size; (void)ws_size;
    const float* ne     = (const float*)d_in[0];
    const float* states = (const float*)d_in[1];
    const float* pf     = (const float*)d_in[2];
    const int*   idx    = (const int*)d_in[3];
    const float* team   = (const float*)d_in[4];
    const float* Ws     = (const float*)d_in[5];
    const float* bs     = (const float*)d_in[6];
    const float* W1     = (const float*)d_in[7];
    const float* b1     = (const float*)d_in[8];
    const float* W2     = (const float*)d_in[9];
    const float* b2     = (const float*)d_in[10];
    const float* W3     = (const float*)d_in[11];
    const float* b3     = (const float*)d_in[12];
    float* out = (float*)d_out;

    char* ws = (char*)d_ws;
    float* gpart    = (float*)(ws + 0);        // 65536
    f16_t* vecs     = (f16_t*)(ws + 65536);    // 393216
    f16_t* W1abcT   = (f16_t*)(ws + 458752);   // 393216
    f16_t* W1dT     = (f16_t*)(ws + 851968);   // 131072
    f16_t* WsT      = (f16_t*)(ws + 983040);   // 65536
    f16_t* W2s      = (f16_t*)(ws + 1048576);  // 131072
    f16_t* w1pt     = (f16_t*)(ws + 1179648);  // 16384
    f16_t* states_h = (f16_t*)(ws + 1196032);  // 131072
    f16_t* pa_h     = (f16_t*)(ws + 1327104);  // 131072
    f16_t* pbt_h    = (f16_t*)(ws + 1458176);  // 262144 (end 1720320)

    k_colsum_part<<<64, 256, 0, stream>>>(ne, gpart);
    k_prep<<<2464, 256, 0, stream>>>(ne, idx, team, gpart, states, Ws, W1, W2,
                                     vecs, W1abcT, W1dT, WsT, W2s, w1pt, states_h);
    k_pp<<<24, 256, 0, stream>>>(states_h, WsT, bs, W1dT, vecs, W1abcT, b1, pa_h, pbt_h);
    k_main<<<M_TOTAL / 128, 512, 0, stream>>>(pf, pa_h, pbt_h, W2s, w1pt, b2, W3, b3, out);
}

// Round 5
// 52.983 us; speedup vs baseline: 1.4675x; 1.3023x over previous
//
#include <hip/hip_runtime.h>
#include <hip/hip_bf16.h>

#define N_NODES 2048
#define EMBED 256
#define STATE 128
#define HID 256
#define N_ACT 256
#define TEAMS 8
#define PAIR_F 14
#define BT_TOTAL 512               // B*T
#define M_TOTAL (BT_TOTAL * N_ACT) // 131072

typedef _Float16 f16_t;
typedef _Float16 f16x8 __attribute__((ext_vector_type(8)));
typedef _Float16 f16x4 __attribute__((ext_vector_type(4)));
typedef float f32x4 __attribute__((ext_vector_type(4)));

// reordered weight layout: for (k, n), KB = K/32:
//   flat = (((n>>4)*KB + (k>>5))*4 + ((k>>3)&3))*128 + (n&15)*8 + (k&7)
// -> a wave (lanes c,q) reading frag (g=n>>4, kb=k>>5) touches contiguous 1KB.
__device__ __forceinline__ size_t reord_idx(int k, int n, int KB) {
    return (size_t)(((n >> 4) * KB + (k >> 5)) * 4 + ((k >> 3) & 3)) * 128 +
           (size_t)(n & 15) * 8 + (k & 7);
}

// paR fragment layout for coalesced phase-1 reads:
//   addr_halves(a, n) = (a>>4)*4096 + (n>>2)*64 + (a&15)*4 + (n&3)
__device__ __forceinline__ size_t par_idx(int a, int n) {
    return (size_t)(a >> 4) * 4096 + (size_t)(n >> 2) * 64 + (a & 15) * 4 + (n & 3);
}

// ---------------- L1: colsum + gathers + weight reorders ----------------
// blocks 0..63: gpart (column partial sums of node_embeddings, 32 nodes each)
// remaining blocks: flat-indexed segments.
__global__ void k_prep(const float* __restrict__ ne, const int* __restrict__ idx,
                       const float* __restrict__ team, const float* __restrict__ states,
                       const float* __restrict__ Ws, const float* __restrict__ W1,
                       const float* __restrict__ W2, float* __restrict__ gpart,
                       f16_t* __restrict__ vecs, f16_t* __restrict__ W1abT,
                       f16_t* __restrict__ W1dT, f16_t* __restrict__ WsT,
                       f16_t* __restrict__ W2s, f16_t* __restrict__ w1pt,
                       f16_t* __restrict__ states_h) {
    int bid = blockIdx.x;
    if (bid < 64) {
        int t = threadIdx.x;
        float s = 0.f;
        const float* base = ne + (size_t)bid * 32 * EMBED + t;
#pragma unroll
        for (int i = 0; i < 32; ++i) s += base[(size_t)i * EMBED];
        gpart[bid * EMBED + t] = s;
        return;
    }
    int i = (bid - 64) * 256 + threadIdx.x;
    if (i < 131072) { // vecs [256][512] = [proc | team]
        int a = i >> 9, e = i & 511;
        float v = (e < 256) ? ne[(size_t)idx[a] * EMBED + e]
                            : team[(a % TEAMS) * EMBED + (e - 256)];
        vecs[i] = (f16_t)v;
        return;
    }
    i -= 131072;
    if (i < 131072) { // W1abT: W1[0:512] reorder KB=16
        int k = i >> 8, n = i & 255;
        W1abT[reord_idx(k, n, 16)] = (f16_t)W1[(size_t)k * HID + n];
        return;
    }
    i -= 131072;
    if (i < 65536) { // W1dT: W1[768:1024] reorder KB=8
        int k = i >> 8, n = i & 255;
        W1dT[reord_idx(k, n, 8)] = (f16_t)W1[(size_t)(768 + k) * HID + n];
        return;
    }
    i -= 65536;
    if (i < 32768) { // WsT KB=4
        int k = i >> 8, n = i & 255;
        WsT[reord_idx(k, n, 4)] = (f16_t)Ws[(size_t)k * EMBED + n];
        return;
    }
    i -= 32768;
    if (i < 65536) { // W2s KB=8
        int k = i >> 8, n = i & 255;
        W2s[reord_idx(k, n, 8)] = (f16_t)W2[(size_t)k * HID + n];
        return;
    }
    i -= 65536;
    if (i < 8192) { // w1pt: W1[1024:1038] pad K->32, KB=1
        int k = i >> 8, n = i & 255;
        float v = (k < PAIR_F) ? W1[(size_t)(1024 + k) * HID + n] : 0.f;
        w1pt[reord_idx(k, n, 1)] = (f16_t)v;
        return;
    }
    i -= 8192;
    if (i < 65536) states_h[i] = (f16_t)states[i];
}

// ---------------- L2: pa (paR layout) + pbt ----------------
// blocks 0..7 : pbt rows bt0..+63: se = relu(states@Ws+bs) in LDS, pbt = se@W1d
// blocks 8..23: pa tile 64x64: vecs@W1ab (K=512) + cvec(gmean.W1c) + b1 -> paR
__global__ __launch_bounds__(256, 4) void k_pp(
    const f16_t* __restrict__ states_h, const f16_t* __restrict__ WsT,
    const float* __restrict__ bs, const f16_t* __restrict__ W1dT,
    const f16_t* __restrict__ vecs, const f16_t* __restrict__ W1abT,
    const float* __restrict__ W1, const float* __restrict__ b1,
    const float* __restrict__ gpart, f16_t* __restrict__ paR,
    f16_t* __restrict__ pbt_h) {
    __shared__ __align__(16) f16_t se[64 * 256]; // pbt path
    __shared__ float gm[256];                    // pa path
    const int tid = threadIdx.x;
    const int wid = tid >> 6, lane = tid & 63;
    const int c = lane & 15, q = lane >> 4;
    int bid = blockIdx.x;

    if (bid >= 8) { // ---- pa path ----
        int b = bid - 8;
        const int m0 = (b >> 2) * 64, n0 = (b & 3) * 64;
        const int n = n0 + wid * 16 + c;
        const int g = n >> 4;
        f32x4 acc[4] = {f32x4{0,0,0,0}, f32x4{0,0,0,0}, f32x4{0,0,0,0}, f32x4{0,0,0,0}};
        for (int ks = 0; ks < 16; ++ks) {
            f16x8 bf = *(const f16x8*)(W1abT + (size_t)((g * 16 + ks) * 4 + q) * 128 + c * 8);
#pragma unroll
            for (int mi = 0; mi < 4; ++mi) {
                f16x8 af = *(const f16x8*)(vecs + (size_t)(m0 + mi * 16 + c) * 512 + ks * 32 + q * 8);
                acc[mi] = __builtin_amdgcn_mfma_f32_16x16x32_f16(af, bf, acc[mi], 0, 0, 0);
            }
        }
        // gmean into LDS
        {
            float s = 0.f;
#pragma unroll 8
            for (int p = 0; p < 64; ++p) s += gpart[p * EMBED + tid];
            gm[tid] = s * (1.0f / N_NODES);
        }
        __syncthreads();
        // cvec[n] = sum_e gm[e] * W1[512+e][n]
        float cvec = 0.f;
#pragma unroll 8
        for (int e = 0; e < 256; ++e)
            cvec = fmaf(gm[e], W1[(size_t)(512 + e) * HID + n], cvec);
        cvec += b1[n];
#pragma unroll
        for (int mi = 0; mi < 4; ++mi)
#pragma unroll
            for (int j = 0; j < 4; ++j) {
                int a = m0 + mi * 16 + q * 4 + j;
                paR[par_idx(a, n)] = (f16_t)(acc[mi][j] + cvec);
            }
        return;
    }

    // ---- pbt path ----
    const int bt0 = bid * 64;
    f32x4 acc[4][4];
#pragma unroll
    for (int mi = 0; mi < 4; ++mi)
#pragma unroll
        for (int ni = 0; ni < 4; ++ni) acc[mi][ni] = f32x4{0, 0, 0, 0};
    // phase A: se = relu(states@Ws + bs)
#pragma unroll
    for (int ks = 0; ks < 4; ++ks) {
        f16x8 bh[4];
#pragma unroll
        for (int ni = 0; ni < 4; ++ni) {
            int g = wid * 4 + ni;
            bh[ni] = *(const f16x8*)(WsT + (size_t)((g * 4 + ks) * 4 + q) * 128 + c * 8);
        }
#pragma unroll
        for (int mi = 0; mi < 4; ++mi) {
            f16x8 af = *(const f16x8*)(states_h + (size_t)(bt0 + mi * 16 + c) * STATE + ks * 32 + q * 8);
#pragma unroll
            for (int ni = 0; ni < 4; ++ni)
                acc[mi][ni] = __builtin_amdgcn_mfma_f32_16x16x32_f16(af, bh[ni], acc[mi][ni], 0, 0, 0);
        }
    }
#pragma unroll
    for (int mi = 0; mi < 4; ++mi)
#pragma unroll
        for (int ni = 0; ni < 4; ++ni) {
            float bsv = bs[wid * 64 + ni * 16 + c];
#pragma unroll
            for (int j = 0; j < 4; ++j) {
                int m = mi * 16 + q * 4 + j;
                int n = wid * 64 + ni * 16 + c;
                se[m * 256 + (n ^ ((m & 7) << 3))] = (f16_t)fmaxf(acc[mi][ni][j] + bsv, 0.f);
            }
        }
#pragma unroll
    for (int mi = 0; mi < 4; ++mi)
#pragma unroll
        for (int ni = 0; ni < 4; ++ni) acc[mi][ni] = f32x4{0, 0, 0, 0};
    __syncthreads();
    // phase B: pbt = se @ W1d (K=256)
#pragma unroll
    for (int ks = 0; ks < 8; ++ks) {
        f16x8 bh[4];
#pragma unroll
        for (int ni = 0; ni < 4; ++ni) {
            int g = wid * 4 + ni;
            bh[ni] = *(const f16x8*)(W1dT + (size_t)((g * 8 + ks) * 4 + q) * 128 + c * 8);
        }
#pragma unroll
        for (int mi = 0; mi < 4; ++mi) {
            int m = mi * 16 + c;
            f16x8 ah = *(const f16x8*)(&se[m * 256 + ((ks * 32 + q * 8) ^ ((m & 7) << 3))]);
#pragma unroll
            for (int ni = 0; ni < 4; ++ni)
                acc[mi][ni] = __builtin_amdgcn_mfma_f32_16x16x32_f16(ah, bh[ni], acc[mi][ni], 0, 0, 0);
        }
    }
#pragma unroll
    for (int mi = 0; mi < 4; ++mi)
#pragma unroll
        for (int ni = 0; ni < 4; ++ni)
#pragma unroll
            for (int j = 0; j < 4; ++j)
                pbt_h[(size_t)(bt0 + mi * 16 + q * 4 + j) * HID + wid * 64 + ni * 16 + c] =
                    (f16_t)acc[mi][ni][j];
}

// ---------------- L3: fused main kernel ----------------
// 256 threads / 4 waves; tile 64 rows x 256 cols; wave = 64 rows x 64-col quarter.
// 33 KB LDS -> 4 blocks/CU -> 16 waves/CU; lean registers (no cross-phase preloads).
__global__ __launch_bounds__(256, 4) void k_main(
    const float* __restrict__ pf, const f16_t* __restrict__ paR,
    const f16_t* __restrict__ pbt, const f16_t* __restrict__ w2s,
    const f16_t* __restrict__ w1pt, const float* __restrict__ b2,
    const float* __restrict__ W3, const float* __restrict__ b3,
    float* __restrict__ out) {
    __shared__ __align__(16) f16_t Ah[64 * 256];
    __shared__ float red[4][64];

    const int tid = threadIdx.x;
    const int wc = tid >> 6, lane = tid & 63;
    const int c = lane & 15, q = lane >> 4;

    const int r0 = blockIdx.x * 64;
    const int bt = r0 >> 8;
    const int a0 = r0 & 255;

    f32x4 acc[16];
#pragma unroll
    for (int i = 0; i < 16; ++i) acc[i] = f32x4{0, 0, 0, 0};

    // ---- phase 1: transposed pair GEMM: D[n][m] = w1pt (A) x pf^T (B)
    f16x8 af[4];
#pragma unroll
    for (int nf = 0; nf < 4; ++nf) {
        int g = wc * 4 + nf;
        af[nf] = *(const f16x8*)(w1pt + (size_t)(g * 4 + q) * 128 + c * 8);
    }
#pragma unroll
    for (int mf = 0; mf < 4; ++mf) {
        int m = mf * 16 + c;
        const float* row = pf + (size_t)(r0 + m) * PAIR_F;
        float2 v01{0, 0}, v23{0, 0}, v45{0, 0}, v67{0, 0};
        if (q == 0) {
            v01 = *(const float2*)(row);
            v23 = *(const float2*)(row + 2);
            v45 = *(const float2*)(row + 4);
            v67 = *(const float2*)(row + 6);
        } else if (q == 1) {
            v01 = *(const float2*)(row + 8);
            v23 = *(const float2*)(row + 10);
            v45 = *(const float2*)(row + 12); // k=12,13; rest padded 0
        }
        f16x8 bf;
        bf[0] = (f16_t)v01.x; bf[1] = (f16_t)v01.y;
        bf[2] = (f16_t)v23.x; bf[3] = (f16_t)v23.y;
        bf[4] = (f16_t)v45.x; bf[5] = (f16_t)v45.y;
        bf[6] = (f16_t)v67.x; bf[7] = (f16_t)v67.y;
#pragma unroll
        for (int nf = 0; nf < 4; ++nf)
            acc[nf * 4 + mf] = __builtin_amdgcn_mfma_f32_16x16x32_f16(af[nf], bf, acc[nf * 4 + mf], 0, 0, 0);
    }

    // ---- h1 = relu(pair + pa + pbt) -> fp16, swizzled LDS
#pragma unroll
    for (int nf = 0; nf < 4; ++nf) {
        int n0 = wc * 64 + nf * 16 + q * 4;
        f16x4 pbtv = *(const f16x4*)(pbt + (size_t)bt * HID + n0); // uniform row
#pragma unroll
        for (int mf = 0; mf < 4; ++mf) {
            int m = mf * 16 + c;
            // paR coalesced: halves addr = (a0/16+mf)*4096 + (n0>>2)*64 + c*4
            f16x4 pav = *(const f16x4*)(paR + (size_t)((a0 >> 4) + mf) * 4096 +
                                        (size_t)(n0 >> 2) * 64 + c * 4);
            f16x4 hv;
#pragma unroll
            for (int j = 0; j < 4; ++j) {
                float h = acc[nf * 4 + mf][j] + (float)pav[j] + (float)pbtv[j];
                hv[j] = (f16_t)fmaxf(h, 0.f);
            }
            *(f16x4*)(&Ah[m * 256 + (n0 ^ ((m & 7) << 3))]) = hv;
        }
    }

#pragma unroll
    for (int i = 0; i < 16; ++i) acc[i] = f32x4{0, 0, 0, 0};

    __syncthreads();

    // ---- phase 2: h2 = h1[64x256] @ W2[256x256]; wave computes 64 rows x 64 cols
#pragma unroll
    for (int ks = 0; ks < 8; ++ks) {
        f16x8 bh[4];
#pragma unroll
        for (int ni = 0; ni < 4; ++ni) {
            int g = wc * 4 + ni;
            bh[ni] = *(const f16x8*)(w2s + (size_t)((g * 8 + ks) * 4 + q) * 128 + c * 8);
        }
#pragma unroll
        for (int mi = 0; mi < 4; ++mi) {
            int m = mi * 16 + c;
            int kx = (ks * 32 + q * 8) ^ ((m & 7) << 3);
            f16x8 ah = *(const f16x8*)(&Ah[m * 256 + kx]);
#pragma unroll
            for (int ni = 0; ni < 4; ++ni)
                acc[mi * 4 + ni] = __builtin_amdgcn_mfma_f32_16x16x32_f16(ah, bh[ni], acc[mi * 4 + ni], 0, 0, 0);
        }
    }

    // ---- epilogue: score[m] = sum_n relu(h2 + b2) * W3 (+ b3)
    float p[4][4];
#pragma unroll
    for (int mi = 0; mi < 4; ++mi)
#pragma unroll
        for (int j = 0; j < 4; ++j) p[mi][j] = 0.f;
#pragma unroll
    for (int ni = 0; ni < 4; ++ni) {
        int n = wc * 64 + ni * 16 + c;
        float b2v = b2[n];
        float w3v = W3[n];
#pragma unroll
        for (int mi = 0; mi < 4; ++mi)
#pragma unroll
            for (int j = 0; j < 4; ++j)
                p[mi][j] = fmaf(fmaxf(acc[mi * 4 + ni][j] + b2v, 0.f), w3v, p[mi][j]);
    }
#pragma unroll
    for (int off = 1; off < 16; off <<= 1)
#pragma unroll
        for (int mi = 0; mi < 4; ++mi)
#pragma unroll
            for (int j = 0; j < 4; ++j) p[mi][j] += __shfl_xor(p[mi][j], off, 64);

    if (c == 0) {
#pragma unroll
        for (int mi = 0; mi < 4; ++mi)
#pragma unroll
            for (int j = 0; j < 4; ++j) red[wc][mi * 16 + q * 4 + j] = p[mi][j];
    }
    __syncthreads();

    if (tid < 64) {
        out[(size_t)r0 + tid] = red[0][tid] + red[1][tid] + red[2][tid] + red[3][tid] + b3[0];
    }
}

// ---------------- launch ----------------
extern "C" void kernel_launch(void* const* d_in, const int* in_sizes, int n_in,
                              void* d_out, int out_size, void* d_ws, size_t ws_size,
                              hipStream_t stream) {
    (void)in_sizes; (void)n_in; (void)out_size; (void)ws_size;
    const float* ne     = (const float*)d_in[0];
    const float* states = (const float*)d_in[1];
    const float* pf     = (const float*)d_in[2];
    const int*   idx    = (const int*)d_in[3];
    const float* team   = (const float*)d_in[4];
    const float* Ws     = (const float*)d_in[5];
    const float* bs     = (const float*)d_in[6];
    const float* W1     = (const float*)d_in[7];
    const float* b1     = (const float*)d_in[8];
    const float* W2     = (const float*)d_in[9];
    const float* b2     = (const float*)d_in[10];
    const float* W3     = (const float*)d_in[11];
    const float* b3     = (const float*)d_in[12];
    float* out = (float*)d_out;

    char* ws = (char*)d_ws;
    float* gpart    = (float*)(ws + 0);        //  65536
    f16_t* vecs     = (f16_t*)(ws + 65536);    // 262144  [256][512]
    f16_t* W1abT    = (f16_t*)(ws + 327680);   // 262144
    f16_t* W1dT     = (f16_t*)(ws + 589824);   // 131072
    f16_t* WsT      = (f16_t*)(ws + 720896);   //  65536
    f16_t* W2s      = (f16_t*)(ws + 786432);   // 131072
    f16_t* w1pt     = (f16_t*)(ws + 917504);   //  16384
    f16_t* states_h = (f16_t*)(ws + 933888);   // 131072
    f16_t* paR      = (f16_t*)(ws + 1064960);  // 131072
    f16_t* pbt_h    = (f16_t*)(ws + 1196032);  // 262144  (end 1458176)

    k_prep<<<64 + 1952, 256, 0, stream>>>(ne, idx, team, states, Ws, W1, W2,
                                          gpart, vecs, W1abT, W1dT, WsT, W2s, w1pt, states_h);
    k_pp<<<24, 256, 0, stream>>>(states_h, WsT, bs, W1dT, vecs, W1abT, W1, b1,
                                 gpart, paR, pbt_h);
    k_main<<<M_TOTAL / 64, 256, 0, stream>>>(pf, paR, pbt_h, W2s, w1pt, b2, W3, b3, out);
}

// Round 6
// 51.852 us; speedup vs baseline: 1.4995x; 1.0218x over previous
//
#include <hip/hip_runtime.h>
#include <hip/hip_bf16.h>

#define N_NODES 2048
#define EMBED 256
#define STATE 128
#define HID 256
#define N_ACT 256
#define TEAMS 8
#define PAIR_F 14
#define BT_TOTAL 512               // B*T
#define M_TOTAL (BT_TOTAL * N_ACT) // 131072

typedef _Float16 f16_t;
typedef _Float16 f16x8 __attribute__((ext_vector_type(8)));
typedef _Float16 f16x4 __attribute__((ext_vector_type(4)));
typedef float f32x4 __attribute__((ext_vector_type(4)));

// reordered weight layout: for (k, n), KB = K/32:
//   flat = (((n>>4)*KB + (k>>5))*4 + ((k>>3)&3))*128 + (n&15)*8 + (k&7)
// -> a wave (lanes c,q) reading frag (g=n>>4, kb=k>>5) touches contiguous 1KB.
__device__ __forceinline__ size_t reord_idx(int k, int n, int KB) {
    return (size_t)(((n >> 4) * KB + (k >> 5)) * 4 + ((k >> 3) & 3)) * 128 +
           (size_t)(n & 15) * 8 + (k & 7);
}

// paR fragment layout for coalesced phase-1 reads:
//   addr_halves(a, n) = (a>>4)*4096 + (n>>2)*64 + (a&15)*4 + (n&3)
__device__ __forceinline__ size_t par_idx(int a, int n) {
    return (size_t)(a >> 4) * 4096 + (size_t)(n >> 2) * 64 + (a & 15) * 4 + (n & 3);
}

// ---------------- L0: column partial sums of node_embeddings ----------------
__global__ void k_cs(const float* __restrict__ ne, float* __restrict__ gpart) {
    int b = blockIdx.x;
    int t = threadIdx.x;
    float s = 0.f;
    const float* base = ne + (size_t)b * 32 * EMBED + t;
#pragma unroll
    for (int i = 0; i < 32; ++i) s += base[(size_t)i * EMBED];
    gpart[b * EMBED + t] = s;
}

// ---------------- L1: gathers + weight reorders + gmean finalize ----------------
__global__ void k_prep(const float* __restrict__ ne, const int* __restrict__ idx,
                       const float* __restrict__ team, const float* __restrict__ states,
                       const float* __restrict__ Ws, const float* __restrict__ W1,
                       const float* __restrict__ W2, const float* __restrict__ gpart,
                       f16_t* __restrict__ vecs, f16_t* __restrict__ W1abT,
                       f16_t* __restrict__ W1cT, f16_t* __restrict__ W1dT,
                       f16_t* __restrict__ WsT, f16_t* __restrict__ W2s,
                       f16_t* __restrict__ w1pt, f16_t* __restrict__ states_h,
                       f16_t* __restrict__ gm_h) {
    int i = blockIdx.x * 256 + threadIdx.x;
    if (i < 131072) { // vecs [256][512] = [proc | team]
        int a = i >> 9, e = i & 511;
        float v = (e < 256) ? ne[(size_t)idx[a] * EMBED + e]
                            : team[(a % TEAMS) * EMBED + (e - 256)];
        vecs[i] = (f16_t)v;
        return;
    }
    i -= 131072;
    if (i < 131072) { // W1abT: W1[0:512] reorder KB=16
        int k = i >> 8, n = i & 255;
        W1abT[reord_idx(k, n, 16)] = (f16_t)W1[(size_t)k * HID + n];
        return;
    }
    i -= 131072;
    if (i < 65536) { // W1cT: W1[512:768] reorder KB=8
        int k = i >> 8, n = i & 255;
        W1cT[reord_idx(k, n, 8)] = (f16_t)W1[(size_t)(512 + k) * HID + n];
        return;
    }
    i -= 65536;
    if (i < 65536) { // W1dT: W1[768:1024] reorder KB=8
        int k = i >> 8, n = i & 255;
        W1dT[reord_idx(k, n, 8)] = (f16_t)W1[(size_t)(768 + k) * HID + n];
        return;
    }
    i -= 65536;
    if (i < 32768) { // WsT KB=4
        int k = i >> 8, n = i & 255;
        WsT[reord_idx(k, n, 4)] = (f16_t)Ws[(size_t)k * EMBED + n];
        return;
    }
    i -= 32768;
    if (i < 65536) { // W2s KB=8
        int k = i >> 8, n = i & 255;
        W2s[reord_idx(k, n, 8)] = (f16_t)W2[(size_t)k * HID + n];
        return;
    }
    i -= 65536;
    if (i < 8192) { // w1pt: W1[1024:1038] pad K->32, KB=1
        int k = i >> 8, n = i & 255;
        float v = (k < PAIR_F) ? W1[(size_t)(1024 + k) * HID + n] : 0.f;
        w1pt[reord_idx(k, n, 1)] = (f16_t)v;
        return;
    }
    i -= 8192;
    if (i < 65536) { states_h[i] = (f16_t)states[i]; return; }
    i -= 65536;
    if (i < 256) { // gmean finalize (f16)
        float s = 0.f;
#pragma unroll 8
        for (int p = 0; p < 64; ++p) s += gpart[p * EMBED + i];
        gm_h[i] = (f16_t)(s * (1.0f / N_NODES));
    }
}

// ---------------- L2: pa (paR layout) + pbt ----------------
// blocks 0..7 : pbt rows bt0..+63: se = relu(states@Ws+bs) in LDS, pbt = se@W1d
// blocks 8..23: pa tile 64x64: [proc|team|gmean]@W1[0:768] + b1 -> paR
//              (gmean ksteps use a lane-uniform A-fragment from gm_h)
__global__ __launch_bounds__(256, 4) void k_pp(
    const f16_t* __restrict__ states_h, const f16_t* __restrict__ WsT,
    const float* __restrict__ bs, const f16_t* __restrict__ W1dT,
    const f16_t* __restrict__ vecs, const f16_t* __restrict__ W1abT,
    const f16_t* __restrict__ W1cT, const f16_t* __restrict__ gm_h,
    const float* __restrict__ b1, f16_t* __restrict__ paR,
    f16_t* __restrict__ pbt_h) {
    __shared__ __align__(16) f16_t se[64 * 256]; // pbt path only
    const int tid = threadIdx.x;
    const int wid = tid >> 6, lane = tid & 63;
    const int c = lane & 15, q = lane >> 4;
    int bid = blockIdx.x;

    if (bid >= 8) { // ---- pa path ----
        int b = bid - 8;
        const int m0 = (b >> 2) * 64, n0 = (b & 3) * 64;
        const int n = n0 + wid * 16 + c;
        const int g = n >> 4;
        f32x4 acc[4] = {f32x4{0,0,0,0}, f32x4{0,0,0,0}, f32x4{0,0,0,0}, f32x4{0,0,0,0}};
        // ks 0..15: proc|team  (A from vecs)
        for (int ks = 0; ks < 16; ++ks) {
            f16x8 bf = *(const f16x8*)(W1abT + (size_t)((g * 16 + ks) * 4 + q) * 128 + c * 8);
#pragma unroll
            for (int mi = 0; mi < 4; ++mi) {
                f16x8 af = *(const f16x8*)(vecs + (size_t)(m0 + mi * 16 + c) * 512 + ks * 32 + q * 8);
                acc[mi] = __builtin_amdgcn_mfma_f32_16x16x32_f16(af, bf, acc[mi], 0, 0, 0);
            }
        }
        // ks 16..23: gmean (A uniform across rows)
#pragma unroll
        for (int ks = 0; ks < 8; ++ks) {
            f16x8 bf = *(const f16x8*)(W1cT + (size_t)((g * 8 + ks) * 4 + q) * 128 + c * 8);
            f16x8 af = *(const f16x8*)(gm_h + ks * 32 + q * 8);
#pragma unroll
            for (int mi = 0; mi < 4; ++mi)
                acc[mi] = __builtin_amdgcn_mfma_f32_16x16x32_f16(af, bf, acc[mi], 0, 0, 0);
        }
        float b1v = b1[n];
#pragma unroll
        for (int mi = 0; mi < 4; ++mi)
#pragma unroll
            for (int j = 0; j < 4; ++j) {
                int a = m0 + mi * 16 + q * 4 + j;
                paR[par_idx(a, n)] = (f16_t)(acc[mi][j] + b1v);
            }
        return;
    }

    // ---- pbt path ----
    const int bt0 = bid * 64;
    f32x4 acc[4][4];
#pragma unroll
    for (int mi = 0; mi < 4; ++mi)
#pragma unroll
        for (int ni = 0; ni < 4; ++ni) acc[mi][ni] = f32x4{0, 0, 0, 0};
    // phase A: se = relu(states@Ws + bs)
#pragma unroll
    for (int ks = 0; ks < 4; ++ks) {
        f16x8 bh[4];
#pragma unroll
        for (int ni = 0; ni < 4; ++ni) {
            int g = wid * 4 + ni;
            bh[ni] = *(const f16x8*)(WsT + (size_t)((g * 4 + ks) * 4 + q) * 128 + c * 8);
        }
#pragma unroll
        for (int mi = 0; mi < 4; ++mi) {
            f16x8 af = *(const f16x8*)(states_h + (size_t)(bt0 + mi * 16 + c) * STATE + ks * 32 + q * 8);
#pragma unroll
            for (int ni = 0; ni < 4; ++ni)
                acc[mi][ni] = __builtin_amdgcn_mfma_f32_16x16x32_f16(af, bh[ni], acc[mi][ni], 0, 0, 0);
        }
    }
#pragma unroll
    for (int mi = 0; mi < 4; ++mi)
#pragma unroll
        for (int ni = 0; ni < 4; ++ni) {
            float bsv = bs[wid * 64 + ni * 16 + c];
#pragma unroll
            for (int j = 0; j < 4; ++j) {
                int m = mi * 16 + q * 4 + j;
                int n = wid * 64 + ni * 16 + c;
                se[m * 256 + (n ^ ((m & 7) << 3))] = (f16_t)fmaxf(acc[mi][ni][j] + bsv, 0.f);
            }
        }
#pragma unroll
    for (int mi = 0; mi < 4; ++mi)
#pragma unroll
        for (int ni = 0; ni < 4; ++ni) acc[mi][ni] = f32x4{0, 0, 0, 0};
    __syncthreads();
    // phase B: pbt = se @ W1d (K=256)
#pragma unroll
    for (int ks = 0; ks < 8; ++ks) {
        f16x8 bh[4];
#pragma unroll
        for (int ni = 0; ni < 4; ++ni) {
            int g = wid * 4 + ni;
            bh[ni] = *(const f16x8*)(W1dT + (size_t)((g * 8 + ks) * 4 + q) * 128 + c * 8);
        }
#pragma unroll
        for (int mi = 0; mi < 4; ++mi) {
            int m = mi * 16 + c;
            f16x8 ah = *(const f16x8*)(&se[m * 256 + ((ks * 32 + q * 8) ^ ((m & 7) << 3))]);
#pragma unroll
            for (int ni = 0; ni < 4; ++ni)
                acc[mi][ni] = __builtin_amdgcn_mfma_f32_16x16x32_f16(ah, bh[ni], acc[mi][ni], 0, 0, 0);
        }
    }
#pragma unroll
    for (int mi = 0; mi < 4; ++mi)
#pragma unroll
        for (int ni = 0; ni < 4; ++ni)
#pragma unroll
            for (int j = 0; j < 4; ++j)
                pbt_h[(size_t)(bt0 + mi * 16 + q * 4 + j) * HID + wid * 64 + ni * 16 + c] =
                    (f16_t)acc[mi][ni][j];
}

// ---------------- L3: fused main kernel ----------------
// 256 threads / 4 waves; tile 64 rows x 256 cols; wave = 64 rows x 64-col quarter.
// ~37 KB LDS -> 4 blocks/CU -> 16 waves/CU; lean registers.
__global__ __launch_bounds__(256, 4) void k_main(
    const float* __restrict__ pf, const f16_t* __restrict__ paR,
    const f16_t* __restrict__ pbt, const f16_t* __restrict__ w2s,
    const f16_t* __restrict__ w1pt, const float* __restrict__ b2,
    const float* __restrict__ W3, const float* __restrict__ b3,
    float* __restrict__ out) {
    __shared__ __align__(16) f16_t Ah[64 * 256];
    __shared__ __align__(16) float pfs[64 * PAIR_F];
    __shared__ float red[4][64];

    const int tid = threadIdx.x;
    const int wc = tid >> 6, lane = tid & 63;
    const int c = lane & 15, q = lane >> 4;

    const int r0 = blockIdx.x * 64;
    const int bt = r0 >> 8;
    const int a0 = r0 & 255;

    // stage 64x14 pair features (contiguous 3584 B, fully coalesced)
    if (tid < 224) {
        const float4 v = ((const float4*)(pf + (size_t)r0 * PAIR_F))[tid];
        *(float4*)&pfs[tid * 4] = v;
    }

    f32x4 acc[16];
#pragma unroll
    for (int i = 0; i < 16; ++i) acc[i] = f32x4{0, 0, 0, 0};

    // phase-1 A fragments (w1pt) — global, before barrier
    f16x8 af[4];
#pragma unroll
    for (int nf = 0; nf < 4; ++nf) {
        int g = wc * 4 + nf;
        af[nf] = *(const f16x8*)(w1pt + (size_t)(g * 4 + q) * 128 + c * 8);
    }

    __syncthreads();

    // ---- phase 1: transposed pair GEMM: D[n][m] = w1pt (A) x pf^T (B)
#pragma unroll
    for (int mf = 0; mf < 4; ++mf) {
        int m = mf * 16 + c;
        f16x8 bf;
#pragma unroll
        for (int j = 0; j < 8; ++j) {
            int k = q * 8 + j;
            float v = (q < 2 && k < PAIR_F) ? pfs[m * PAIR_F + k] : 0.f;
            bf[j] = (f16_t)v;
        }
#pragma unroll
        for (int nf = 0; nf < 4; ++nf)
            acc[nf * 4 + mf] = __builtin_amdgcn_mfma_f32_16x16x32_f16(af[nf], bf, acc[nf * 4 + mf], 0, 0, 0);
    }

    // ---- h1 = relu(pair + pa + pbt) -> fp16, swizzled LDS
#pragma unroll
    for (int nf = 0; nf < 4; ++nf) {
        int n0 = wc * 64 + nf * 16 + q * 4;
        f16x4 pbtv = *(const f16x4*)(pbt + (size_t)bt * HID + n0); // uniform row
#pragma unroll
        for (int mf = 0; mf < 4; ++mf) {
            int m = mf * 16 + c;
            f16x4 pav = *(const f16x4*)(paR + (size_t)((a0 >> 4) + mf) * 4096 +
                                        (size_t)(n0 >> 2) * 64 + c * 4);
            f16x4 hv;
#pragma unroll
            for (int j = 0; j < 4; ++j) {
                float h = acc[nf * 4 + mf][j] + (float)pav[j] + (float)pbtv[j];
                hv[j] = (f16_t)fmaxf(h, 0.f);
            }
            *(f16x4*)(&Ah[m * 256 + (n0 ^ ((m & 7) << 3))]) = hv;
        }
    }

#pragma unroll
    for (int i = 0; i < 16; ++i) acc[i] = f32x4{0, 0, 0, 0};

    __syncthreads();

    // ---- phase 2: h2 = h1[64x256] @ W2[256x256]; 1-deep B prefetch pipeline
    f16x8 bh[4];
#pragma unroll
    for (int ni = 0; ni < 4; ++ni) {
        int g = wc * 4 + ni;
        bh[ni] = *(const f16x8*)(w2s + (size_t)((g * 8 + 0) * 4 + q) * 128 + c * 8);
    }
#pragma unroll
    for (int ks = 0; ks < 8; ++ks) {
        f16x8 bhn[4];
        if (ks < 7) {
#pragma unroll
            for (int ni = 0; ni < 4; ++ni) {
                int g = wc * 4 + ni;
                bhn[ni] = *(const f16x8*)(w2s + (size_t)((g * 8 + ks + 1) * 4 + q) * 128 + c * 8);
            }
        }
#pragma unroll
        for (int mi = 0; mi < 4; ++mi) {
            int m = mi * 16 + c;
            int kx = (ks * 32 + q * 8) ^ ((m & 7) << 3);
            f16x8 ah = *(const f16x8*)(&Ah[m * 256 + kx]);
#pragma unroll
            for (int ni = 0; ni < 4; ++ni)
                acc[mi * 4 + ni] = __builtin_amdgcn_mfma_f32_16x16x32_f16(ah, bh[ni], acc[mi * 4 + ni], 0, 0, 0);
        }
#pragma unroll
        for (int ni = 0; ni < 4; ++ni) bh[ni] = bhn[ni];
    }

    // ---- epilogue: score[m] = sum_n relu(h2 + b2) * W3 (+ b3)
    float p[4][4];
#pragma unroll
    for (int mi = 0; mi < 4; ++mi)
#pragma unroll
        for (int j = 0; j < 4; ++j) p[mi][j] = 0.f;
#pragma unroll
    for (int ni = 0; ni < 4; ++ni) {
        int n = wc * 64 + ni * 16 + c;
        float b2v = b2[n];
        float w3v = W3[n];
#pragma unroll
        for (int mi = 0; mi < 4; ++mi)
#pragma unroll
            for (int j = 0; j < 4; ++j)
                p[mi][j] = fmaf(fmaxf(acc[mi * 4 + ni][j] + b2v, 0.f), w3v, p[mi][j]);
    }
#pragma unroll
    for (int off = 1; off < 16; off <<= 1)
#pragma unroll
        for (int mi = 0; mi < 4; ++mi)
#pragma unroll
            for (int j = 0; j < 4; ++j) p[mi][j] += __shfl_xor(p[mi][j], off, 64);

    if (c == 0) {
#pragma unroll
        for (int mi = 0; mi < 4; ++mi)
#pragma unroll
            for (int j = 0; j < 4; ++j) red[wc][mi * 16 + q * 4 + j] = p[mi][j];
    }
    __syncthreads();

    if (tid < 64) {
        out[(size_t)r0 + tid] = red[0][tid] + red[1][tid] + red[2][tid] + red[3][tid] + b3[0];
    }
}

// ---------------- launch ----------------
extern "C" void kernel_launch(void* const* d_in, const int* in_sizes, int n_in,
                              void* d_out, int out_size, void* d_ws, size_t ws_size,
                              hipStream_t stream) {
    (void)in_sizes; (void)n_in; (void)out_size; (void)ws_size;
    const float* ne     = (const float*)d_in[0];
    const float* states = (const float*)d_in[1];
    const float* pf     = (const float*)d_in[2];
    const int*   idx    = (const int*)d_in[3];
    const float* team   = (const float*)d_in[4];
    const float* Ws     = (const float*)d_in[5];
    const float* bs     = (const float*)d_in[6];
    const float* W1     = (const float*)d_in[7];
    const float* b1     = (const float*)d_in[8];
    const float* W2     = (const float*)d_in[9];
    const float* b2     = (const float*)d_in[10];
    const float* W3     = (const float*)d_in[11];
    const float* b3     = (const float*)d_in[12];
    float* out = (float*)d_out;

    char* ws = (char*)d_ws;
    float* gpart    = (float*)(ws + 0);        //  65536
    f16_t* vecs     = (f16_t*)(ws + 65536);    // 262144  [256][512]
    f16_t* W1abT    = (f16_t*)(ws + 327680);   // 262144
    f16_t* W1cT     = (f16_t*)(ws + 589824);   // 131072
    f16_t* W1dT     = (f16_t*)(ws + 720896);   // 131072
    f16_t* WsT      = (f16_t*)(ws + 851968);   //  65536
    f16_t* W2s      = (f16_t*)(ws + 917504);   // 131072
    f16_t* w1pt     = (f16_t*)(ws + 1048576);  //  16384
    f16_t* states_h = (f16_t*)(ws + 1064960);  // 131072
    f16_t* gm_h     = (f16_t*)(ws + 1196032);  //    512
    f16_t* paR      = (f16_t*)(ws + 1196544);  // 131072
    f16_t* pbt_h    = (f16_t*)(ws + 1327616);  // 262144  (end 1589760)

    k_cs<<<64, 256, 0, stream>>>(ne, gpart);
    // segments: 131072+131072+65536+65536+32768+65536+8192+65536+256 = 565504 -> 2209 blocks
    k_prep<<<2209, 256, 0, stream>>>(ne, idx, team, states, Ws, W1, W2, gpart,
                                     vecs, W1abT, W1cT, W1dT, WsT, W2s, w1pt,
                                     states_h, gm_h);
    k_pp<<<24, 256, 0, stream>>>(states_h, WsT, bs, W1dT, vecs, W1abT, W1cT,
                                 gm_h, b1, paR, pbt_h);
    k_main<<<M_TOTAL / 64, 256, 0, stream>>>(pf, paR, pbt_h, W2s, w1pt, b2, W3, b3, out);
}

// Round 7
// 49.691 us; speedup vs baseline: 1.5647x; 1.0435x over previous
//
#include <hip/hip_runtime.h>
#include <hip/hip_bf16.h>

#define N_NODES 2048
#define EMBED 256
#define STATE 128
#define HID 256
#define N_ACT 256
#define TEAMS 8
#define PAIR_F 14
#define BT_TOTAL 512               // B*T
#define M_TOTAL (BT_TOTAL * N_ACT) // 131072

typedef _Float16 f16_t;
typedef _Float16 f16x8 __attribute__((ext_vector_type(8)));
typedef _Float16 f16x4 __attribute__((ext_vector_type(4)));
typedef float f32x4 __attribute__((ext_vector_type(4)));

// reordered weight layout: for (k, n), KB = K/32:
//   flat = (((n>>4)*KB + (k>>5))*4 + ((k>>3)&3))*128 + (n&15)*8 + (k&7)
// -> a wave (lanes c,q) reading frag (g=n>>4, kb=k>>5) touches contiguous 1KB.
__device__ __forceinline__ size_t reord_idx(int k, int n, int KB) {
    return (size_t)(((n >> 4) * KB + (k >> 5)) * 4 + ((k >> 3) & 3)) * 128 +
           (size_t)(n & 15) * 8 + (k & 7);
}

// paR fragment layout for coalesced phase-1 reads:
//   addr_halves(a, n) = (a>>4)*4096 + (n>>2)*64 + (a&15)*4 + (n&3)
__device__ __forceinline__ size_t par_idx(int a, int n) {
    return (size_t)(a >> 4) * 4096 + (size_t)(n >> 2) * 64 + (a & 15) * 4 + (n & 3);
}

// convert 8 consecutive W rows' element n into one f16x8 (reord unit)
__device__ __forceinline__ f16x8 gather8(const float* __restrict__ W, int k0, int n, int ld) {
    f16x8 r;
#pragma unroll
    for (int j = 0; j < 8; ++j) r[j] = (f16_t)W[(size_t)(k0 + j) * ld + n];
    return r;
}

// ---------------- L1: colsum + gathers + vectorized weight reorders ----------------
// blocks 0..63: gpart column partial sums (32 nodes each).
// blocks 64.. : one f16x8 (16B) output unit per thread; unit index == output addr/8.
__global__ void k_prep(const float* __restrict__ ne, const int* __restrict__ idx,
                       const float* __restrict__ team, const float* __restrict__ states,
                       const float* __restrict__ Ws, const float* __restrict__ W1,
                       const float* __restrict__ W2, float* __restrict__ gpart,
                       f16_t* __restrict__ vecs, f16_t* __restrict__ W1abT,
                       f16_t* __restrict__ W1cT, f16_t* __restrict__ W1dT,
                       f16_t* __restrict__ WsT, f16_t* __restrict__ W2s,
                       f16_t* __restrict__ w1pt, f16_t* __restrict__ states_h) {
    int bid = blockIdx.x;
    if (bid < 64) {
        int t = threadIdx.x;
        float s = 0.f;
        const float* base = ne + (size_t)bid * 32 * EMBED + t;
#pragma unroll
        for (int i = 0; i < 32; ++i) s += base[(size_t)i * EMBED];
        gpart[bid * EMBED + t] = s;
        return;
    }
    int u = (bid - 64) * 256 + threadIdx.x;
    if (u < 16384) { // vecs [256][512]: unit u -> a=u>>6, e=(u&63)*8
        int a = u >> 6, e = (u & 63) * 8;
        f16x8 r;
        if (e < 256) {
            const float* src = ne + (size_t)idx[a] * EMBED + e;
#pragma unroll
            for (int j = 0; j < 8; ++j) r[j] = (f16_t)src[j];
        } else {
            const float* src = team + (size_t)(a % TEAMS) * EMBED + (e - 256);
#pragma unroll
            for (int j = 0; j < 8; ++j) r[j] = (f16_t)src[j];
        }
        *(f16x8*)(vecs + (size_t)u * 8) = r;
        return;
    }
    u -= 16384;
    if (u < 16384) { // W1abT: KB=16; u = ((g*16+kb)*4+q)*16 + c
        int c = u & 15, q = (u >> 4) & 3, kb = (u >> 6) & 15, g = u >> 10;
        *(f16x8*)(W1abT + (size_t)u * 8) = gather8(W1, kb * 32 + q * 8, g * 16 + c, HID);
        return;
    }
    u -= 16384;
    if (u < 8192) { // W1cT: KB=8, k base 512
        int c = u & 15, q = (u >> 4) & 3, kb = (u >> 6) & 7, g = u >> 9;
        *(f16x8*)(W1cT + (size_t)u * 8) = gather8(W1, 512 + kb * 32 + q * 8, g * 16 + c, HID);
        return;
    }
    u -= 8192;
    if (u < 8192) { // W1dT: KB=8, k base 768
        int c = u & 15, q = (u >> 4) & 3, kb = (u >> 6) & 7, g = u >> 9;
        *(f16x8*)(W1dT + (size_t)u * 8) = gather8(W1, 768 + kb * 32 + q * 8, g * 16 + c, HID);
        return;
    }
    u -= 8192;
    if (u < 4096) { // WsT: KB=4
        int c = u & 15, q = (u >> 4) & 3, kb = (u >> 6) & 3, g = u >> 8;
        *(f16x8*)(WsT + (size_t)u * 8) = gather8(Ws, kb * 32 + q * 8, g * 16 + c, EMBED);
        return;
    }
    u -= 4096;
    if (u < 8192) { // W2s: KB=8
        int c = u & 15, q = (u >> 4) & 3, kb = (u >> 6) & 7, g = u >> 9;
        *(f16x8*)(W2s + (size_t)u * 8) = gather8(W2, kb * 32 + q * 8, g * 16 + c, HID);
        return;
    }
    u -= 8192;
    if (u < 1024) { // w1pt: KB=1, k base 1024, pad K 14->32
        int c = u & 15, q = (u >> 4) & 3, g = u >> 6;
        int n = g * 16 + c, k0 = q * 8;
        f16x8 r;
#pragma unroll
        for (int j = 0; j < 8; ++j) {
            int k = k0 + j;
            r[j] = (f16_t)((k < PAIR_F) ? W1[(size_t)(1024 + k) * HID + n] : 0.f);
        }
        *(f16x8*)(w1pt + (size_t)u * 8) = r;
        return;
    }
    u -= 1024;
    if (u < 8192) { // states_h copy
        const float* src = states + (size_t)u * 8;
        f16x8 r;
#pragma unroll
        for (int j = 0; j < 8; ++j) r[j] = (f16_t)src[j];
        *(f16x8*)(states_h + (size_t)u * 8) = r;
    }
}

// ---------------- L2: pa (paR layout) + pbt ----------------
// blocks 0..7 : pbt rows bt0..+63: se = relu(states@Ws+bs) in LDS, pbt = se@W1d
// blocks 8..23: pa tile 64x64: [proc|team|gmean]@W1[0:768] + b1 -> paR
//              (gmean computed in-block from gpart; MFMA fold via W1cT)
__global__ __launch_bounds__(256, 4) void k_pp(
    const f16_t* __restrict__ states_h, const f16_t* __restrict__ WsT,
    const float* __restrict__ bs, const f16_t* __restrict__ W1dT,
    const f16_t* __restrict__ vecs, const f16_t* __restrict__ W1abT,
    const f16_t* __restrict__ W1cT, const float* __restrict__ gpart,
    const float* __restrict__ b1, f16_t* __restrict__ paR,
    f16_t* __restrict__ pbt_h) {
    __shared__ __align__(16) f16_t se[64 * 256]; // pbt path only
    __shared__ __align__(16) f16_t gml[256];     // pa path only
    const int tid = threadIdx.x;
    const int wid = tid >> 6, lane = tid & 63;
    const int c = lane & 15, q = lane >> 4;
    int bid = blockIdx.x;

    if (bid >= 8) { // ---- pa path ----
        // gmean into LDS (coalesced gpart column sums)
        {
            float s = 0.f;
#pragma unroll 8
            for (int p = 0; p < 64; ++p) s += gpart[p * EMBED + tid];
            gml[tid] = (f16_t)(s * (1.0f / N_NODES));
        }
        __syncthreads();
        int b = bid - 8;
        const int m0 = (b >> 2) * 64, n0 = (b & 3) * 64;
        const int n = n0 + wid * 16 + c;
        const int g = n >> 4;
        f32x4 acc[4] = {f32x4{0,0,0,0}, f32x4{0,0,0,0}, f32x4{0,0,0,0}, f32x4{0,0,0,0}};
        // ks 0..15: proc|team (A from vecs)
        for (int ks = 0; ks < 16; ++ks) {
            f16x8 bf = *(const f16x8*)(W1abT + (size_t)((g * 16 + ks) * 4 + q) * 128 + c * 8);
#pragma unroll
            for (int mi = 0; mi < 4; ++mi) {
                f16x8 af = *(const f16x8*)(vecs + (size_t)(m0 + mi * 16 + c) * 512 + ks * 32 + q * 8);
                acc[mi] = __builtin_amdgcn_mfma_f32_16x16x32_f16(af, bf, acc[mi], 0, 0, 0);
            }
        }
        // ks 16..23: gmean (A uniform across rows, from LDS broadcast)
#pragma unroll
        for (int ks = 0; ks < 8; ++ks) {
            f16x8 bf = *(const f16x8*)(W1cT + (size_t)((g * 8 + ks) * 4 + q) * 128 + c * 8);
            f16x8 af = *(const f16x8*)(gml + ks * 32 + q * 8);
#pragma unroll
            for (int mi = 0; mi < 4; ++mi)
                acc[mi] = __builtin_amdgcn_mfma_f32_16x16x32_f16(af, bf, acc[mi], 0, 0, 0);
        }
        float b1v = b1[n];
#pragma unroll
        for (int mi = 0; mi < 4; ++mi)
#pragma unroll
            for (int j = 0; j < 4; ++j) {
                int a = m0 + mi * 16 + q * 4 + j;
                paR[par_idx(a, n)] = (f16_t)(acc[mi][j] + b1v);
            }
        return;
    }

    // ---- pbt path ----
    const int bt0 = bid * 64;
    f32x4 acc[4][4];
#pragma unroll
    for (int mi = 0; mi < 4; ++mi)
#pragma unroll
        for (int ni = 0; ni < 4; ++ni) acc[mi][ni] = f32x4{0, 0, 0, 0};
    // phase A: se = relu(states@Ws + bs)
#pragma unroll
    for (int ks = 0; ks < 4; ++ks) {
        f16x8 bh[4];
#pragma unroll
        for (int ni = 0; ni < 4; ++ni) {
            int g = wid * 4 + ni;
            bh[ni] = *(const f16x8*)(WsT + (size_t)((g * 4 + ks) * 4 + q) * 128 + c * 8);
        }
#pragma unroll
        for (int mi = 0; mi < 4; ++mi) {
            f16x8 af = *(const f16x8*)(states_h + (size_t)(bt0 + mi * 16 + c) * STATE + ks * 32 + q * 8);
#pragma unroll
            for (int ni = 0; ni < 4; ++ni)
                acc[mi][ni] = __builtin_amdgcn_mfma_f32_16x16x32_f16(af, bh[ni], acc[mi][ni], 0, 0, 0);
        }
    }
#pragma unroll
    for (int mi = 0; mi < 4; ++mi)
#pragma unroll
        for (int ni = 0; ni < 4; ++ni) {
            float bsv = bs[wid * 64 + ni * 16 + c];
#pragma unroll
            for (int j = 0; j < 4; ++j) {
                int m = mi * 16 + q * 4 + j;
                int n = wid * 64 + ni * 16 + c;
                se[m * 256 + (n ^ ((m & 7) << 3))] = (f16_t)fmaxf(acc[mi][ni][j] + bsv, 0.f);
            }
        }
#pragma unroll
    for (int mi = 0; mi < 4; ++mi)
#pragma unroll
        for (int ni = 0; ni < 4; ++ni) acc[mi][ni] = f32x4{0, 0, 0, 0};
    __syncthreads();
    // phase B: pbt = se @ W1d (K=256)
#pragma unroll
    for (int ks = 0; ks < 8; ++ks) {
        f16x8 bh[4];
#pragma unroll
        for (int ni = 0; ni < 4; ++ni) {
            int g = wid * 4 + ni;
            bh[ni] = *(const f16x8*)(W1dT + (size_t)((g * 8 + ks) * 4 + q) * 128 + c * 8);
        }
#pragma unroll
        for (int mi = 0; mi < 4; ++mi) {
            int m = mi * 16 + c;
            f16x8 ah = *(const f16x8*)(&se[m * 256 + ((ks * 32 + q * 8) ^ ((m & 7) << 3))]);
#pragma unroll
            for (int ni = 0; ni < 4; ++ni)
                acc[mi][ni] = __builtin_amdgcn_mfma_f32_16x16x32_f16(ah, bh[ni], acc[mi][ni], 0, 0, 0);
        }
    }
#pragma unroll
    for (int mi = 0; mi < 4; ++mi)
#pragma unroll
        for (int ni = 0; ni < 4; ++ni)
#pragma unroll
            for (int j = 0; j < 4; ++j)
                pbt_h[(size_t)(bt0 + mi * 16 + q * 4 + j) * HID + wid * 64 + ni * 16 + c] =
                    (f16_t)acc[mi][ni][j];
}

// ---------------- L3: fused main kernel (unchanged from round 6) ----------------
__global__ __launch_bounds__(256, 4) void k_main(
    const float* __restrict__ pf, const f16_t* __restrict__ paR,
    const f16_t* __restrict__ pbt, const f16_t* __restrict__ w2s,
    const f16_t* __restrict__ w1pt, const float* __restrict__ b2,
    const float* __restrict__ W3, const float* __restrict__ b3,
    float* __restrict__ out) {
    __shared__ __align__(16) f16_t Ah[64 * 256];
    __shared__ __align__(16) float pfs[64 * PAIR_F];
    __shared__ float red[4][64];

    const int tid = threadIdx.x;
    const int wc = tid >> 6, lane = tid & 63;
    const int c = lane & 15, q = lane >> 4;

    const int r0 = blockIdx.x * 64;
    const int bt = r0 >> 8;
    const int a0 = r0 & 255;

    // stage 64x14 pair features (contiguous 3584 B, fully coalesced)
    if (tid < 224) {
        const float4 v = ((const float4*)(pf + (size_t)r0 * PAIR_F))[tid];
        *(float4*)&pfs[tid * 4] = v;
    }

    f32x4 acc[16];
#pragma unroll
    for (int i = 0; i < 16; ++i) acc[i] = f32x4{0, 0, 0, 0};

    // phase-1 A fragments (w1pt) — global, before barrier
    f16x8 af[4];
#pragma unroll
    for (int nf = 0; nf < 4; ++nf) {
        int g = wc * 4 + nf;
        af[nf] = *(const f16x8*)(w1pt + (size_t)(g * 4 + q) * 128 + c * 8);
    }

    __syncthreads();

    // ---- phase 1: transposed pair GEMM: D[n][m] = w1pt (A) x pf^T (B)
#pragma unroll
    for (int mf = 0; mf < 4; ++mf) {
        int m = mf * 16 + c;
        f16x8 bf;
#pragma unroll
        for (int j = 0; j < 8; ++j) {
            int k = q * 8 + j;
            float v = (q < 2 && k < PAIR_F) ? pfs[m * PAIR_F + k] : 0.f;
            bf[j] = (f16_t)v;
        }
#pragma unroll
        for (int nf = 0; nf < 4; ++nf)
            acc[nf * 4 + mf] = __builtin_amdgcn_mfma_f32_16x16x32_f16(af[nf], bf, acc[nf * 4 + mf], 0, 0, 0);
    }

    // ---- h1 = relu(pair + pa + pbt) -> fp16, swizzled LDS
#pragma unroll
    for (int nf = 0; nf < 4; ++nf) {
        int n0 = wc * 64 + nf * 16 + q * 4;
        f16x4 pbtv = *(const f16x4*)(pbt + (size_t)bt * HID + n0); // uniform row
#pragma unroll
        for (int mf = 0; mf < 4; ++mf) {
            int m = mf * 16 + c;
            f16x4 pav = *(const f16x4*)(paR + (size_t)((a0 >> 4) + mf) * 4096 +
                                        (size_t)(n0 >> 2) * 64 + c * 4);
            f16x4 hv;
#pragma unroll
            for (int j = 0; j < 4; ++j) {
                float h = acc[nf * 4 + mf][j] + (float)pav[j] + (float)pbtv[j];
                hv[j] = (f16_t)fmaxf(h, 0.f);
            }
            *(f16x4*)(&Ah[m * 256 + (n0 ^ ((m & 7) << 3))]) = hv;
        }
    }

#pragma unroll
    for (int i = 0; i < 16; ++i) acc[i] = f32x4{0, 0, 0, 0};

    __syncthreads();

    // ---- phase 2: h2 = h1[64x256] @ W2[256x256]; 1-deep B prefetch pipeline
    f16x8 bh[4];
#pragma unroll
    for (int ni = 0; ni < 4; ++ni) {
        int g = wc * 4 + ni;
        bh[ni] = *(const f16x8*)(w2s + (size_t)((g * 8 + 0) * 4 + q) * 128 + c * 8);
    }
#pragma unroll
    for (int ks = 0; ks < 8; ++ks) {
        f16x8 bhn[4];
        if (ks < 7) {
#pragma unroll
            for (int ni = 0; ni < 4; ++ni) {
                int g = wc * 4 + ni;
                bhn[ni] = *(const f16x8*)(w2s + (size_t)((g * 8 + ks + 1) * 4 + q) * 128 + c * 8);
            }
        }
#pragma unroll
        for (int mi = 0; mi < 4; ++mi) {
            int m = mi * 16 + c;
            int kx = (ks * 32 + q * 8) ^ ((m & 7) << 3);
            f16x8 ah = *(const f16x8*)(&Ah[m * 256 + kx]);
#pragma unroll
            for (int ni = 0; ni < 4; ++ni)
                acc[mi * 4 + ni] = __builtin_amdgcn_mfma_f32_16x16x32_f16(ah, bh[ni], acc[mi * 4 + ni], 0, 0, 0);
        }
#pragma unroll
        for (int ni = 0; ni < 4; ++ni) bh[ni] = bhn[ni];
    }

    // ---- epilogue: score[m] = sum_n relu(h2 + b2) * W3 (+ b3)
    float p[4][4];
#pragma unroll
    for (int mi = 0; mi < 4; ++mi)
#pragma unroll
        for (int j = 0; j < 4; ++j) p[mi][j] = 0.f;
#pragma unroll
    for (int ni = 0; ni < 4; ++ni) {
        int n = wc * 64 + ni * 16 + c;
        float b2v = b2[n];
        float w3v = W3[n];
#pragma unroll
        for (int mi = 0; mi < 4; ++mi)
#pragma unroll
            for (int j = 0; j < 4; ++j)
                p[mi][j] = fmaf(fmaxf(acc[mi * 4 + ni][j] + b2v, 0.f), w3v, p[mi][j]);
    }
#pragma unroll
    for (int off = 1; off < 16; off <<= 1)
#pragma unroll
        for (int mi = 0; mi < 4; ++mi)
#pragma unroll
            for (int j = 0; j < 4; ++j) p[mi][j] += __shfl_xor(p[mi][j], off, 64);

    if (c == 0) {
#pragma unroll
        for (int mi = 0; mi < 4; ++mi)
#pragma unroll
            for (int j = 0; j < 4; ++j) red[wc][mi * 16 + q * 4 + j] = p[mi][j];
    }
    __syncthreads();

    if (tid < 64) {
        out[(size_t)r0 + tid] = red[0][tid] + red[1][tid] + red[2][tid] + red[3][tid] + b3[0];
    }
}

// ---------------- launch ----------------
extern "C" void kernel_launch(void* const* d_in, const int* in_sizes, int n_in,
                              void* d_out, int out_size, void* d_ws, size_t ws_size,
                              hipStream_t stream) {
    (void)in_sizes; (void)n_in; (void)out_size; (void)ws_size;
    const float* ne     = (const float*)d_in[0];
    const float* states = (const float*)d_in[1];
    const float* pf     = (const float*)d_in[2];
    const int*   idx    = (const int*)d_in[3];
    const float* team   = (const float*)d_in[4];
    const float* Ws     = (const float*)d_in[5];
    const float* bs     = (const float*)d_in[6];
    const float* W1     = (const float*)d_in[7];
    const float* b1     = (const float*)d_in[8];
    const float* W2     = (const float*)d_in[9];
    const float* b2     = (const float*)d_in[10];
    const float* W3     = (const float*)d_in[11];
    const float* b3     = (const float*)d_in[12];
    float* out = (float*)d_out;

    char* ws = (char*)d_ws;
    float* gpart    = (float*)(ws + 0);        //  65536
    f16_t* vecs     = (f16_t*)(ws + 65536);    // 262144  [256][512]
    f16_t* W1abT    = (f16_t*)(ws + 327680);   // 262144
    f16_t* W1cT     = (f16_t*)(ws + 589824);   // 131072
    f16_t* W1dT     = (f16_t*)(ws + 720896);   // 131072
    f16_t* WsT      = (f16_t*)(ws + 851968);   //  65536
    f16_t* W2s      = (f16_t*)(ws + 917504);   // 131072
    f16_t* w1pt     = (f16_t*)(ws + 1048576);  //  16384
    f16_t* states_h = (f16_t*)(ws + 1064960);  // 131072
    f16_t* paR      = (f16_t*)(ws + 1196032);  // 131072
    f16_t* pbt_h    = (f16_t*)(ws + 1327104);  // 262144  (end 1589248)

    // units: 16384(vecs)+16384(W1abT)+8192(W1cT)+8192(W1dT)+4096(WsT)
    //        +8192(W2s)+1024(w1pt)+8192(states_h) = 70656 -> 276 blocks (+64 colsum)
    k_prep<<<64 + 276, 256, 0, stream>>>(ne, idx, team, states, Ws, W1, W2, gpart,
                                         vecs, W1abT, W1cT, W1dT, WsT, W2s, w1pt,
                                         states_h);
    k_pp<<<24, 256, 0, stream>>>(states_h, WsT, bs, W1dT, vecs, W1abT, W1cT,
                                 gpart, b1, paR, pbt_h);
    k_main<<<M_TOTAL / 64, 256, 0, stream>>>(pf, paR, pbt_h, W2s, w1pt, b2, W3, b3, out);
}